// Round 1
// baseline (1092.502 us; speedup 1.0000x reference)
//
#include <hip/hip_runtime.h>

#define NN 2048
#define BB 8
#define LDC 80   // padded basis column count (66 -> 80)

typedef __bf16 bf16;
typedef __bf16 bf16x4 __attribute__((ext_vector_type(4)));
typedef __bf16 bf16x8 __attribute__((ext_vector_type(8)));
typedef float  f32x4  __attribute__((ext_vector_type(4)));

// ---------------------------------------------------------------------------
// K0: fold Chebyshev T2 = 2*A^2*x - x and duplicated-X blocks into weights.
// weg[t][c][o] (5x66x96), weu[t][c][o] (5x66x32)
// ---------------------------------------------------------------------------
__global__ void prep_weights(const float* __restrict__ gw, const float* __restrict__ uw,
                             float* __restrict__ weg, float* __restrict__ weu)
{
    int i = blockIdx.x * 256 + threadIdx.x;
    if (i < 5 * 66 * 96) {
        int t = i / (66 * 96), rc = i % (66 * 96), c = rc / 96, o = rc % 96;
        float v;
        if (t == 0)      v = gw[c*96+o] - gw[(132+c)*96+o] + gw[(198+c)*96+o] - gw[(330+c)*96+o];
        else if (t == 1) v = gw[(66+c)*96+o];
        else if (t == 2) v = 2.0f * gw[(132+c)*96+o];
        else if (t == 3) v = gw[(264+c)*96+o];
        else             v = 2.0f * gw[(330+c)*96+o];
        weg[i] = v;
    }
    if (i < 5 * 66 * 32) {
        int t = i / (66 * 32), rc = i % (66 * 32), c = rc / 32, o = rc % 32;
        float v;
        if (t == 0)      v = uw[c*32+o] - uw[(132+c)*32+o] + uw[(198+c)*32+o] - uw[(330+c)*32+o];
        else if (t == 1) v = uw[(66+c)*32+o];
        else if (t == 2) v = 2.0f * uw[(132+c)*32+o];
        else if (t == 3) v = uw[(264+c)*32+o];
        else             v = 2.0f * uw[(330+c)*32+o];
        weu[i] = v;
    }
}

// ---------------------------------------------------------------------------
// K1: per-node mr = sigmoid(gate_in @ mlp_w + b), state = mr*s1+(1-mr)*s2,
// and build transposed bf16 basis X^T (80 x 2048 per batch, pad rows zeroed).
// block = 256 threads = 8 nodes x 32 channels
// ---------------------------------------------------------------------------
__global__ __launch_bounds__(256)
void prep_nodes(const float* __restrict__ xt, const float* __restrict__ s1,
                const float* __restrict__ s2, const float* __restrict__ ge,
                const float* __restrict__ mlp_w, const float* __restrict__ mlp_b,
                float* __restrict__ state, bf16* __restrict__ Xgt)
{
    __shared__ float w[74 * 32];
    const int tid = threadIdx.x;
    for (int i = tid; i < 74 * 32; i += 256) w[i] = mlp_w[i];
    __syncthreads();
    const int g = tid >> 5, c = tid & 31;
    const size_t node = (size_t)blockIdx.x * 8 + g;
    const int b = (int)(node >> 11), n = (int)(node & 2047);
    const float* px = xt + node * 2;
    const float* p1 = s1 + node * 32;
    const float* p2 = s2 + node * 32;
    const float* pg = ge + node * 8;
    float acc = mlp_b[c];
    #pragma unroll
    for (int i = 0; i < 2; ++i)  acc += px[i] * w[i*32 + c];
    for (int i = 0; i < 32; ++i) acc += p1[i] * w[(2+i)*32 + c];
    for (int i = 0; i < 32; ++i) acc += p2[i] * w[(34+i)*32 + c];
    #pragma unroll
    for (int i = 0; i < 8; ++i)  acc += pg[i] * w[(66+i)*32 + c];
    float mr = 1.0f / (1.0f + __expf(-acc));
    float v1 = p1[c], v2 = p2[c];
    state[node*32 + c] = mr * v1 + (1.0f - mr) * v2;
    bf16* X = Xgt + (size_t)b * LDC * NN;
    X[(size_t)(2 + c) * NN + n]  = (bf16)v1;
    X[(size_t)(34 + c) * NN + n] = (bf16)v2;
    if (c < 2)  X[(size_t)c * NN + n] = (bf16)px[c];
    if (c < 14) X[(size_t)(66 + c) * NN + n] = (bf16)0.0f;
}

// ---------------------------------------------------------------------------
// K2: C^T(80x2048 bf16) = A(2048x2048 f32) @ B (B given transposed, bf16).
// grid (32 mtiles of 64 rows, 16 = s*8+b). bt_per_sb: B indexed per (s,b) or per b.
// 16x16x32 bf16 MFMA; A converted f32->bf16 during LDS staging; reg-prefetch
// double-buffered LDS, one barrier per K-iter.
// ---------------------------------------------------------------------------
__global__ __launch_bounds__(256, 2)
void gemm_cheb(const float* __restrict__ Aall, const bf16* __restrict__ Btall,
               bf16* __restrict__ Ctall, int bt_per_sb)
{
    __shared__ __align__(16) bf16 lA[2][64][40];
    __shared__ __align__(16) bf16 lB[2][80][40];

    const int sb = blockIdx.y;
    const int m0 = blockIdx.x * 64;
    const float* A  = Aall + (size_t)sb * NN * NN + (size_t)m0 * NN;
    const bf16*  Bt = Btall + (size_t)(bt_per_sb ? sb : (sb & 7)) * LDC * NN;
    bf16*        Ct = Ctall + (size_t)sb * LDC * NN + m0;

    const int tid  = threadIdx.x;
    const int wave = tid >> 6;
    const int lane = tid & 63;

    const int arow = tid >> 3;        // 0..31 (phase0), +32 (phase1)
    const int aseg = tid & 7;         // 4 f32 each
    const int brow = tid >> 2;        // 0..63
    const int bseg = tid & 3;         // 8 bf16 each
    const int brow2 = 64 + (tid >> 2); // rows 64..79, tid<64 only

    float4 ra0, ra1;
    uint4  rb0, rb1;

    auto gload = [&](int k0) {
        ra0 = *(const float4*)(A + (size_t)arow * NN + k0 + aseg * 4);
        ra1 = *(const float4*)(A + (size_t)(arow + 32) * NN + k0 + aseg * 4);
        rb0 = *(const uint4*)(Bt + (size_t)brow * NN + k0 + bseg * 8);
        if (tid < 64)
            rb1 = *(const uint4*)(Bt + (size_t)brow2 * NN + k0 + bseg * 8);
    };
    auto stage = [&](int buf) {
        bf16x4 a0, a1;
        a0[0] = (bf16)ra0.x; a0[1] = (bf16)ra0.y; a0[2] = (bf16)ra0.z; a0[3] = (bf16)ra0.w;
        a1[0] = (bf16)ra1.x; a1[1] = (bf16)ra1.y; a1[2] = (bf16)ra1.z; a1[3] = (bf16)ra1.w;
        *(bf16x4*)&lA[buf][arow][aseg * 4]      = a0;
        *(bf16x4*)&lA[buf][arow + 32][aseg * 4] = a1;
        *(uint4*)&lB[buf][brow][bseg * 8] = rb0;
        if (tid < 64) *(uint4*)&lB[buf][brow2][bseg * 8] = rb1;
    };

    f32x4 acc[5] = {};
    const int frow = lane & 15;
    const int fko  = (lane >> 4) * 8;

    gload(0);
    #pragma unroll 2
    for (int kt = 0; kt < 64; ++kt) {
        const int buf = kt & 1;
        stage(buf);
        if (kt < 63) gload((kt + 1) * 32);
        __syncthreads();
        bf16x8 af = *(const bf16x8*)&lA[buf][wave * 16 + frow][fko];
        #pragma unroll
        for (int ct = 0; ct < 5; ++ct) {
            bf16x8 bv = *(const bf16x8*)&lB[buf][ct * 16 + frow][fko];
            acc[ct] = __builtin_amdgcn_mfma_f32_16x16x32_bf16(af, bv, acc[ct], 0, 0, 0);
        }
    }

    const int ccol = lane & 15;
    const int crow = (lane >> 4) * 4;
    #pragma unroll
    for (int ct = 0; ct < 5; ++ct) {
        bf16x4 o;
        o[0] = (bf16)acc[ct][0]; o[1] = (bf16)acc[ct][1];
        o[2] = (bf16)acc[ct][2]; o[3] = (bf16)acc[ct][3];
        *(bf16x4*)&Ct[(size_t)(ct * 16 + ccol) * NN + wave * 16 + crow] = o;
    }
}

// ---------------------------------------------------------------------------
// K3: gate projection: zz_r = sigmoid(sum_t T_t @ Weff_t + b); build candidate^T
// (bf16, padded) and store r (f32). block = 64 nodes x 4 output-groups of 24.
// ---------------------------------------------------------------------------
__global__ __launch_bounds__(256, 2)
void proj_gate(const bf16* __restrict__ Xgt, const bf16* __restrict__ Y1t,
               const bf16* __restrict__ Z2t, const float* __restrict__ weg,
               const float* __restrict__ gate_b, const float* __restrict__ xt,
               const float* __restrict__ s1, const float* __restrict__ s2,
               bf16* __restrict__ Candt, float* __restrict__ rbuf)
{
    __shared__ __align__(16) bf16  Tl[66][72];
    __shared__ __align__(16) float Wl[66][96];
    const int b  = blockIdx.y;
    const int n0 = blockIdx.x * 64;
    const int tid = threadIdx.x;
    const int nl = tid & 63;
    const int og = tid >> 6;

    const bf16* terms[5];
    terms[0] = Xgt + (size_t)b * LDC * NN;
    terms[1] = Y1t + (size_t)b * LDC * NN;
    terms[2] = Z2t + (size_t)b * LDC * NN;
    terms[3] = Y1t + (size_t)(8 + b) * LDC * NN;
    terms[4] = Z2t + (size_t)(8 + b) * LDC * NN;

    float acc[24];
    #pragma unroll
    for (int j = 0; j < 24; ++j) acc[j] = gate_b[og * 24 + j];

    for (int t = 0; t < 5; ++t) {
        for (int i = tid; i < 66 * 16; i += 256) {
            int c = i >> 4, seg = i & 15;
            *(uint2*)&Tl[c][seg * 4] = *(const uint2*)(terms[t] + (size_t)c * NN + n0 + seg * 4);
        }
        const float* wsrc = weg + t * (66 * 96);
        for (int i = tid; i < 66 * 24; i += 256) {
            int c = i / 24, q = i % 24;
            *(float4*)&Wl[c][q * 4] = *(const float4*)(wsrc + c * 96 + q * 4);
        }
        __syncthreads();
        for (int c = 0; c < 66; ++c) {
            float tv = (float)Tl[c][nl];
            const float* wr = &Wl[c][og * 24];
            #pragma unroll
            for (int j = 0; j < 24; ++j) acc[j] += tv * wr[j];
        }
        __syncthreads();
    }

    const int n = n0 + nl;
    const size_t node = (size_t)b * NN + n;
    const float* p1 = s1 + node * 32;
    const float* p2 = s2 + node * 32;
    bf16* C = Candt + (size_t)b * LDC * NN;
    #pragma unroll
    for (int j = 0; j < 24; ++j) {
        int o = og * 24 + j;
        float v = 1.0f / (1.0f + __expf(-acc[j]));
        if (o < 32)      C[(size_t)(2 + o) * NN + n]       = (bf16)(v * p1[o]);
        else if (o < 64) C[(size_t)(34 + (o - 32)) * NN + n] = (bf16)(v * p2[o - 32]);
        else             rbuf[node * 32 + (o - 64)]        = v;
    }
    if (og == 0) {
        C[n]      = (bf16)xt[node * 2 + 0];
        C[NN + n] = (bf16)xt[node * 2 + 1];
        #pragma unroll
        for (int c = 66; c < 80; ++c) C[(size_t)c * NN + n] = (bf16)0.0f;
    }
}

// ---------------------------------------------------------------------------
// K4: update projection: hc = tanh(...), h = r*state+(1-r)*hc, trans = h@hop_w+b.
// block = 64 nodes x 4 output-groups of 8.
// ---------------------------------------------------------------------------
__global__ __launch_bounds__(256, 2)
void proj_upd(const bf16* __restrict__ Candt, const bf16* __restrict__ Y1t,
              const bf16* __restrict__ Z2t, const float* __restrict__ weu,
              const float* __restrict__ upd_b, const float* __restrict__ state,
              const float* __restrict__ rbuf, const float* __restrict__ hop_w,
              const float* __restrict__ hop_b, float* __restrict__ out)
{
    __shared__ __align__(16) bf16  Tl[66][72];
    __shared__ __align__(16) float Wl[66][32];
    __shared__ float hsh[64][33];
    __shared__ float hw[1024];
    const int b  = blockIdx.y;
    const int n0 = blockIdx.x * 64;
    const int tid = threadIdx.x;
    const int nl = tid & 63;
    const int og = tid >> 6;

    const bf16* terms[5];
    terms[0] = Candt + (size_t)b * LDC * NN;
    terms[1] = Y1t + (size_t)b * LDC * NN;
    terms[2] = Z2t + (size_t)b * LDC * NN;
    terms[3] = Y1t + (size_t)(8 + b) * LDC * NN;
    terms[4] = Z2t + (size_t)(8 + b) * LDC * NN;

    for (int i = tid; i < 1024; i += 256) hw[i] = hop_w[i];

    float acc[8];
    #pragma unroll
    for (int j = 0; j < 8; ++j) acc[j] = upd_b[og * 8 + j];

    for (int t = 0; t < 5; ++t) {
        for (int i = tid; i < 66 * 16; i += 256) {
            int c = i >> 4, seg = i & 15;
            *(uint2*)&Tl[c][seg * 4] = *(const uint2*)(terms[t] + (size_t)c * NN + n0 + seg * 4);
        }
        const float* wsrc = weu + t * (66 * 32);
        for (int i = tid; i < 66 * 8; i += 256) {
            int c = i >> 3, q = i & 7;
            *(float4*)&Wl[c][q * 4] = *(const float4*)(wsrc + c * 32 + q * 4);
        }
        __syncthreads();
        for (int c = 0; c < 66; ++c) {
            float tv = (float)Tl[c][nl];
            const float* wr = &Wl[c][og * 8];
            #pragma unroll
            for (int j = 0; j < 8; ++j) acc[j] += tv * wr[j];
        }
        __syncthreads();
    }

    const int n = n0 + nl;
    const size_t node = (size_t)b * NN + n;
    #pragma unroll
    for (int j = 0; j < 8; ++j) {
        int o = og * 8 + j;
        float hc = tanhf(acc[j]);
        float r  = rbuf[node * 32 + o];
        float h  = r * state[node * 32 + o] + (1.0f - r) * hc;
        out[node * 32 + o] = h;
        hsh[nl][o] = h;
    }
    __syncthreads();
    float* out2 = out + (size_t)BB * NN * 32;
    #pragma unroll
    for (int j = 0; j < 8; ++j) {
        int o = og * 8 + j;
        float t = hop_b[o];
        #pragma unroll
        for (int k = 0; k < 32; ++k) t += hsh[nl][k] * hw[k * 32 + o];
        out2[node * 32 + o] = t;
    }
}

// ---------------------------------------------------------------------------
extern "C" void kernel_launch(void* const* d_in, const int* in_sizes, int n_in,
                              void* d_out, int out_size, void* d_ws, size_t ws_size,
                              hipStream_t stream)
{
    const float* xt     = (const float*)d_in[0];
    const float* s1     = (const float*)d_in[1];
    const float* s2     = (const float*)d_in[2];
    const float* ge     = (const float*)d_in[3];
    const float* sup    = (const float*)d_in[4];
    const float* mlp_w  = (const float*)d_in[5];
    const float* mlp_b  = (const float*)d_in[6];
    const float* gate_w = (const float*)d_in[7];
    const float* gate_b = (const float*)d_in[8];
    const float* upd_w  = (const float*)d_in[9];
    const float* upd_b  = (const float*)d_in[10];
    const float* hop_w  = (const float*)d_in[11];
    const float* hop_b  = (const float*)d_in[12];
    float* out = (float*)d_out;

    char* ws = (char*)d_ws;
    size_t off = 0;
    auto alloc = [&](size_t bytes) -> void* {
        void* p = ws + off;
        off += (bytes + 255) & ~(size_t)255;
        return p;
    };
    bf16*  Xgt   = (bf16*)alloc((size_t)BB * LDC * NN * 2);
    bf16*  Candt = (bf16*)alloc((size_t)BB * LDC * NN * 2);
    bf16*  Y1t   = (bf16*)alloc((size_t)16 * LDC * NN * 2);
    bf16*  Z2t   = (bf16*)alloc((size_t)16 * LDC * NN * 2);
    float* state = (float*)alloc((size_t)16384 * 32 * 4);
    float* rbuf  = (float*)alloc((size_t)16384 * 32 * 4);
    float* weg   = (float*)alloc((size_t)5 * 66 * 96 * 4);
    float* weu   = (float*)alloc((size_t)5 * 66 * 32 * 4);

    prep_weights<<<124, 256, 0, stream>>>(gate_w, upd_w, weg, weu);
    prep_nodes<<<2048, 256, 0, stream>>>(xt, s1, s2, ge, mlp_w, mlp_b, state, Xgt);

    // _agcn round 1 (gate): Y1 = A@X, Z2 = A@Y1
    gemm_cheb<<<dim3(32, 16), 256, 0, stream>>>(sup, Xgt, Y1t, 0);
    gemm_cheb<<<dim3(32, 16), 256, 0, stream>>>(sup, Y1t, Z2t, 1);
    proj_gate<<<dim3(32, 8), 256, 0, stream>>>(Xgt, Y1t, Z2t, weg, gate_b, xt, s1, s2, Candt, rbuf);

    // _agcn round 2 (update): Y1 = A@cand, Z2 = A@Y1
    gemm_cheb<<<dim3(32, 16), 256, 0, stream>>>(sup, Candt, Y1t, 0);
    gemm_cheb<<<dim3(32, 16), 256, 0, stream>>>(sup, Y1t, Z2t, 1);
    proj_upd<<<dim3(32, 8), 256, 0, stream>>>(Candt, Y1t, Z2t, weu, upd_b, state, rbuf,
                                              hop_w, hop_b, out);
}

// Round 2
// 584.918 us; speedup vs baseline: 1.8678x; 1.8678x over previous
//
#include <hip/hip_runtime.h>

#define NN 2048
#define BB 8
#define KT 416            // 5 slots * 80 rows + 16 zero pad rows
#define SLOT (80 * NN)

typedef __bf16 bf16;
typedef __bf16 bf16x4 __attribute__((ext_vector_type(4)));
typedef __bf16 bf16x8 __attribute__((ext_vector_type(8)));
typedef float  f32x4  __attribute__((ext_vector_type(4)));

// ---------------------------------------------------------------------------
// K0: fold Chebyshev (T2 = 2A^2x - x) + duplicated-X blocks into transposed
// bf16 weights Wg'[96][416], Wu'[32][416]; k = t*80 + c, pad cols zeroed.
// ---------------------------------------------------------------------------
__global__ void prep_weights(const float* __restrict__ gw, const float* __restrict__ uw,
                             bf16* __restrict__ Wg, bf16* __restrict__ Wu)
{
    int i = blockIdx.x * 256 + threadIdx.x;
    if (i < 96 * KT) {
        int o = i / KT, k = i % KT, t = k / 80, c = k % 80;
        float v = 0.0f;
        if (c < 66) {
            if (t == 0)      v = gw[c*96+o] - gw[(132+c)*96+o] + gw[(198+c)*96+o] - gw[(330+c)*96+o];
            else if (t == 1) v = gw[(66+c)*96+o];
            else if (t == 2) v = 2.0f * gw[(132+c)*96+o];
            else if (t == 3) v = gw[(264+c)*96+o];
            else             v = 2.0f * gw[(330+c)*96+o];
        }
        Wg[i] = (bf16)v;
    }
    if (i < 32 * KT) {
        int o = i / KT, k = i % KT, t = k / 80, c = k % 80;
        float v = 0.0f;
        if (c < 66) {
            if (t == 0)      v = uw[c*32+o] - uw[(132+c)*32+o] + uw[(198+c)*32+o] - uw[(330+c)*32+o];
            else if (t == 1) v = uw[(66+c)*32+o];
            else if (t == 2) v = 2.0f * uw[(132+c)*32+o];
            else if (t == 3) v = uw[(264+c)*32+o];
            else             v = 2.0f * uw[(330+c)*32+o];
        }
        Wu[i] = (bf16)v;
    }
}

// ---------------------------------------------------------------------------
// K1: 64-node tiles. mr = sigmoid(gate_in@mlp_w+b), state = mr*s1+(1-mr)*s2,
// build T slot0 = X^T basis (rows 0..79, pads zero) with coalesced 128B row
// writes via LDS transpose. Also zeroes T pad rows 400..415.
// ---------------------------------------------------------------------------
__global__ __launch_bounds__(256)
void prep_nodes(const float* __restrict__ xt, const float* __restrict__ s1,
                const float* __restrict__ s2, const float* __restrict__ ge,
                const float* __restrict__ mlp_w, const float* __restrict__ mlp_b,
                float* __restrict__ state, bf16* __restrict__ T)
{
    __shared__ float wl[74 * 32];
    __shared__ float bl[32];
    __shared__ __align__(16) float statel[64][36];
    __shared__ __align__(16) bf16  Xl[80][72];
    const int tid = threadIdx.x;

    for (int i = tid; i < 592; i += 256) ((float4*)wl)[i] = ((const float4*)mlp_w)[i];
    if (tid < 32) bl[tid] = mlp_b[tid];
    {   // zero T pad rows (rows 400..415 per batch): this block's 2KB chunk
        int bb = blockIdx.x >> 5, chunk = blockIdx.x & 31;
        uint2* dst = (uint2*)((char*)T + ((size_t)bb * KT * NN + 400 * NN) * 2 + (size_t)chunk * 2048);
        dst[tid] = make_uint2(0u, 0u);
    }
    for (int i = tid; i < 14 * 64; i += 256) Xl[66 + (i >> 6)][i & 63] = (bf16)0.0f;
    __syncthreads();

    const int nl = tid & 63, og = tid >> 6, o0 = og * 8;
    const size_t node0 = (size_t)blockIdx.x * 64;
    const size_t node = node0 + nl;
    const int b = (int)(node0 >> 11);
    const int nb0 = (int)(node0 & 2047);
    const float* p1 = s1 + node * 32;
    const float* p2 = s2 + node * 32;
    const float* pg = ge + node * 8;

    float acc[8];
    #pragma unroll
    for (int j = 0; j < 8; ++j) acc[j] = bl[o0 + j];
    float2 px = *(const float2*)(xt + node * 2);
    #pragma unroll
    for (int j = 0; j < 8; ++j) acc[j] += px.x * wl[o0 + j] + px.y * wl[32 + o0 + j];

    float k1[8], k2[8];
    #pragma unroll
    for (int ii = 0; ii < 8; ++ii) {
        float4 v = *(const float4*)(p1 + ii * 4);
        const float* vp = (const float*)&v;
        if (ii == 2 * og)     { k1[0]=vp[0]; k1[1]=vp[1]; k1[2]=vp[2]; k1[3]=vp[3]; }
        if (ii == 2 * og + 1) { k1[4]=vp[0]; k1[5]=vp[1]; k1[6]=vp[2]; k1[7]=vp[3]; }
        #pragma unroll
        for (int p = 0; p < 4; ++p) {
            #pragma unroll
            for (int j = 0; j < 8; ++j) acc[j] += vp[p] * wl[(2 + ii*4 + p) * 32 + o0 + j];
        }
    }
    #pragma unroll
    for (int ii = 0; ii < 8; ++ii) {
        float4 v = *(const float4*)(p2 + ii * 4);
        const float* vp = (const float*)&v;
        if (ii == 2 * og)     { k2[0]=vp[0]; k2[1]=vp[1]; k2[2]=vp[2]; k2[3]=vp[3]; }
        if (ii == 2 * og + 1) { k2[4]=vp[0]; k2[5]=vp[1]; k2[6]=vp[2]; k2[7]=vp[3]; }
        #pragma unroll
        for (int p = 0; p < 4; ++p) {
            #pragma unroll
            for (int j = 0; j < 8; ++j) acc[j] += vp[p] * wl[(34 + ii*4 + p) * 32 + o0 + j];
        }
    }
    #pragma unroll
    for (int ii = 0; ii < 2; ++ii) {
        float4 v = *(const float4*)(pg + ii * 4);
        const float* vp = (const float*)&v;
        #pragma unroll
        for (int p = 0; p < 4; ++p) {
            #pragma unroll
            for (int j = 0; j < 8; ++j) acc[j] += vp[p] * wl[(66 + ii*4 + p) * 32 + o0 + j];
        }
    }
    #pragma unroll
    for (int j = 0; j < 8; ++j) {
        float mr = 1.0f / (1.0f + __expf(-acc[j]));
        statel[nl][o0 + j] = mr * k1[j] + (1.0f - mr) * k2[j];
        Xl[2 + o0 + j][nl]  = (bf16)k1[j];
        Xl[34 + o0 + j][nl] = (bf16)k2[j];
    }
    if (og == 0) { Xl[0][nl] = (bf16)px.x; Xl[1][nl] = (bf16)px.y; }
    __syncthreads();

    for (int i = tid; i < 512; i += 256) {
        int n_ = i >> 3, c = (i & 7) * 4;
        *(float4*)&state[node0 * 32 + n_ * 32 + c] = *(const float4*)&statel[n_][c];
    }
    bf16* Tb = T + (size_t)b * KT * NN;
    for (int i = tid; i < 640; i += 256) {
        int r = i >> 3, seg = i & 7;
        *(uint4*)(Tb + (size_t)r * NN + nb0 + seg * 8) = *(const uint4*)&Xl[r][seg * 8];
    }
}

// ---------------------------------------------------------------------------
// K2: C^T(80x2048 bf16) = A(2048x2048) @ T-slot. MODE 0: A f32; MODE 1: A f32
// + write bf16 copy to Abf; MODE 2: A bf16 from Abf. Output into T slot.
// ---------------------------------------------------------------------------
template<int MODE>
__global__ __launch_bounds__(256, 2)
void gemm_cheb(const float* __restrict__ Aall, bf16* Abf, bf16* T,
               int in0, int in1, int out0, int out1)
{
    __shared__ __align__(16) bf16 lA[2][64][40];
    __shared__ __align__(16) bf16 lB[2][80][40];

    const int sb = blockIdx.y;
    const int s = sb >> 3, b = sb & 7;
    const int m0 = blockIdx.x * 64;
    const float* A = Aall + (size_t)sb * NN * NN + (size_t)m0 * NN;
    bf16* Ab = Abf + (size_t)sb * NN * NN + (size_t)m0 * NN;
    bf16* Tb = T + (size_t)b * KT * NN;
    const bf16* Bt = Tb + (size_t)(s ? in1 : in0) * SLOT;
    bf16*       Ct = Tb + (size_t)(s ? out1 : out0) * SLOT + m0;

    const int tid  = threadIdx.x;
    const int wave = tid >> 6;
    const int lane = tid & 63;

    const int arow = tid >> 3, aseg = tid & 7;       // MODE 0/1
    const int arw2 = tid >> 2, asg2 = tid & 3;       // MODE 2
    const int brow = tid >> 2, bseg = tid & 3;
    const int brow2 = 64 + (tid >> 2);

    float4 ra0, ra1; uint4 ra2; uint4 rb0, rb1;

    auto gload = [&](int k0) {
        if constexpr (MODE == 2) {
            ra2 = *(const uint4*)(Ab + (size_t)arw2 * NN + k0 + asg2 * 8);
        } else {
            ra0 = *(const float4*)(A + (size_t)arow * NN + k0 + aseg * 4);
            ra1 = *(const float4*)(A + (size_t)(arow + 32) * NN + k0 + aseg * 4);
        }
        rb0 = *(const uint4*)(Bt + (size_t)brow * NN + k0 + bseg * 8);
        if (tid < 64) rb1 = *(const uint4*)(Bt + (size_t)brow2 * NN + k0 + bseg * 8);
    };
    auto stage = [&](int buf, int k0) {
        if constexpr (MODE == 2) {
            *(uint4*)&lA[buf][arw2][asg2 * 8] = ra2;
        } else {
            bf16x4 a0, a1;
            a0[0]=(bf16)ra0.x; a0[1]=(bf16)ra0.y; a0[2]=(bf16)ra0.z; a0[3]=(bf16)ra0.w;
            a1[0]=(bf16)ra1.x; a1[1]=(bf16)ra1.y; a1[2]=(bf16)ra1.z; a1[3]=(bf16)ra1.w;
            *(bf16x4*)&lA[buf][arow][aseg * 4]      = a0;
            *(bf16x4*)&lA[buf][arow + 32][aseg * 4] = a1;
            if constexpr (MODE == 1) {
                *(bf16x4*)(Ab + (size_t)arow * NN + k0 + aseg * 4)        = a0;
                *(bf16x4*)(Ab + (size_t)(arow + 32) * NN + k0 + aseg * 4) = a1;
            }
        }
        *(uint4*)&lB[buf][brow][bseg * 8] = rb0;
        if (tid < 64) *(uint4*)&lB[buf][brow2][bseg * 8] = rb1;
    };

    f32x4 acc[5] = {};
    const int frow = lane & 15;
    const int fko  = (lane >> 4) * 8;

    gload(0);
    #pragma unroll 2
    for (int kt = 0; kt < 64; ++kt) {
        const int buf = kt & 1;
        stage(buf, kt * 32);
        if (kt < 63) gload((kt + 1) * 32);
        __syncthreads();
        bf16x8 af = *(const bf16x8*)&lA[buf][wave * 16 + frow][fko];
        #pragma unroll
        for (int ct = 0; ct < 5; ++ct) {
            bf16x8 bv = *(const bf16x8*)&lB[buf][ct * 16 + frow][fko];
            acc[ct] = __builtin_amdgcn_mfma_f32_16x16x32_bf16(af, bv, acc[ct], 0, 0, 0);
        }
    }

    const int ccol = lane & 15;
    const int crow = (lane >> 4) * 4;
    #pragma unroll
    for (int ct = 0; ct < 5; ++ct) {
        bf16x4 o;
        o[0]=(bf16)acc[ct][0]; o[1]=(bf16)acc[ct][1]; o[2]=(bf16)acc[ct][2]; o[3]=(bf16)acc[ct][3];
        *(bf16x4*)&Ct[(size_t)(ct * 16 + ccol) * NN + wave * 16 + crow] = o;
    }
}

// ---------------------------------------------------------------------------
// K3: gate projection as MFMA GEMM: D[96][2048/b] = Wg'[96][416] @ T[416][2048].
// Weights fully LDS-resident; B-tiles (32k x 64n) double-buffered, transposed
// into [n][k] by scatter. Epilogue: sigmoid, write Cand rows 2..65 (slot0) and
// rT[b][32][2048].
// ---------------------------------------------------------------------------
__global__ __launch_bounds__(256)
void proj_gate(const bf16* T, const bf16* __restrict__ Wg, const float* __restrict__ gate_b,
               const float* __restrict__ s1, const float* __restrict__ s2,
               bf16* Tmut, float* __restrict__ rT)
{
    __shared__ __align__(16) bf16 Wl[96][424];
    __shared__ __align__(16) bf16 Bl[2][64][44];
    const int b = blockIdx.y, n0 = blockIdx.x * 64, tid = threadIdx.x;
    const bf16* Tb = T + (size_t)b * KT * NN;

    for (int i = tid; i < 96 * 52; i += 256) {
        int r = i / 52, seg = i % 52;
        *(uint4*)&Wl[r][seg * 8] = *(const uint4*)(Wg + (size_t)r * KT + seg * 8);
    }
    const int kk = tid >> 3, seg = tid & 7;
    uint4 rb;
    auto gload = [&](int k0) { rb = *(const uint4*)(Tb + (size_t)(k0 + kk) * NN + n0 + seg * 8); };
    auto scat = [&](int buf) {
        bf16 tmp[8]; *(uint4*)tmp = rb;
        #pragma unroll
        for (int j = 0; j < 8; ++j) Bl[buf][seg * 8 + j][kk] = tmp[j];
    };
    const int lane = tid & 63, wave = tid >> 6;
    const int fr = lane & 15, qd = lane >> 4;

    f32x4 acc[6] = {};
    gload(0);
    for (int st = 0; st < 13; ++st) {
        const int buf = st & 1;
        scat(buf);
        if (st < 12) gload((st + 1) * 32);
        __syncthreads();
        bf16x8 bv = *(const bf16x8*)&Bl[buf][wave * 16 + fr][qd * 8];
        #pragma unroll
        for (int f = 0; f < 6; ++f) {
            bf16x8 av = *(const bf16x8*)&Wl[f * 16 + fr][st * 32 + qd * 8];
            acc[f] = __builtin_amdgcn_mfma_f32_16x16x32_bf16(av, bv, acc[f], 0, 0, 0);
        }
    }

    const int nn = n0 + wave * 16 + fr;
    const size_t node = (size_t)b * NN + nn;
    bf16* Cd = Tmut + (size_t)b * KT * NN;   // slot 0
    #pragma unroll
    for (int f = 0; f < 6; ++f) {
        const int o0 = f * 16 + qd * 4;
        float4 gb4 = *(const float4*)(gate_b + o0);
        const float* gb = (const float*)&gb4;
        float sg[4];
        #pragma unroll
        for (int r = 0; r < 4; ++r) sg[r] = 1.0f / (1.0f + __expf(-(acc[f][r] + gb[r])));
        if (f < 2) {
            float4 sv4 = *(const float4*)(s1 + node * 32 + o0);
            const float* sv = (const float*)&sv4;
            #pragma unroll
            for (int r = 0; r < 4; ++r) Cd[(size_t)(2 + o0 + r) * NN + nn] = (bf16)(sg[r] * sv[r]);
        } else if (f < 4) {
            const int oo = o0 - 32;
            float4 sv4 = *(const float4*)(s2 + node * 32 + oo);
            const float* sv = (const float*)&sv4;
            #pragma unroll
            for (int r = 0; r < 4; ++r) Cd[(size_t)(34 + oo + r) * NN + nn] = (bf16)(sg[r] * sv[r]);
        } else {
            const int oo = o0 - 64;
            #pragma unroll
            for (int r = 0; r < 4; ++r) rT[((size_t)b * 32 + oo + r) * NN + nn] = sg[r];
        }
    }
}

// ---------------------------------------------------------------------------
// K4: update projection: D[32][2048/b] = Wu'[32][416] @ T[416][2048];
// hc = tanh, h = r*state+(1-r)*hc, transnext = h@hop_w+b. h staged in LDS for
// the 32-dot and coalesced writes.
// ---------------------------------------------------------------------------
__global__ __launch_bounds__(256)
void proj_upd(const bf16* __restrict__ T, const bf16* __restrict__ Wu,
              const float* __restrict__ upd_b, const float* __restrict__ state,
              const float* __restrict__ rT, const float* __restrict__ hop_w,
              const float* __restrict__ hop_b, float* __restrict__ out)
{
    __shared__ __align__(16) bf16 Wl[32][424];
    __shared__ __align__(16) bf16 Bl[2][64][44];
    __shared__ __align__(16) float hsh[64][36];
    __shared__ float hw[1024];
    const int b = blockIdx.y, n0 = blockIdx.x * 64, tid = threadIdx.x;
    const bf16* Tb = T + (size_t)b * KT * NN;

    for (int i = tid; i < 32 * 52; i += 256) {
        int r = i / 52, seg = i % 52;
        *(uint4*)&Wl[r][seg * 8] = *(const uint4*)(Wu + (size_t)r * KT + seg * 8);
    }
    for (int i = tid; i < 256; i += 256) ((float4*)hw)[i] = ((const float4*)hop_w)[i];
    const int kk = tid >> 3, seg = tid & 7;
    uint4 rb;
    auto gload = [&](int k0) { rb = *(const uint4*)(Tb + (size_t)(k0 + kk) * NN + n0 + seg * 8); };
    auto scat = [&](int buf) {
        bf16 tmp[8]; *(uint4*)tmp = rb;
        #pragma unroll
        for (int j = 0; j < 8; ++j) Bl[buf][seg * 8 + j][kk] = tmp[j];
    };
    const int lane = tid & 63, wave = tid >> 6;
    const int fr = lane & 15, qd = lane >> 4;

    f32x4 acc[2] = {};
    gload(0);
    for (int st = 0; st < 13; ++st) {
        const int buf = st & 1;
        scat(buf);
        if (st < 12) gload((st + 1) * 32);
        __syncthreads();
        bf16x8 bv = *(const bf16x8*)&Bl[buf][wave * 16 + fr][qd * 8];
        #pragma unroll
        for (int f = 0; f < 2; ++f) {
            bf16x8 av = *(const bf16x8*)&Wl[f * 16 + fr][st * 32 + qd * 8];
            acc[f] = __builtin_amdgcn_mfma_f32_16x16x32_bf16(av, bv, acc[f], 0, 0, 0);
        }
    }

    const int nn = n0 + wave * 16 + fr;
    const size_t node = (size_t)b * NN + nn;
    const int nl = wave * 16 + fr;
    #pragma unroll
    for (int f = 0; f < 2; ++f) {
        const int o0 = f * 16 + qd * 4;
        float4 ub4 = *(const float4*)(upd_b + o0);
        const float* ub = (const float*)&ub4;
        float4 st4 = *(const float4*)(state + node * 32 + o0);
        const float* sv = (const float*)&st4;
        #pragma unroll
        for (int r = 0; r < 4; ++r) {
            const int o = o0 + r;
            float hc = tanhf(acc[f][r] + ub[r]);
            float rv = rT[((size_t)b * 32 + o) * NN + nn];
            hsh[nl][o] = rv * sv[r] + (1.0f - rv) * hc;
        }
    }
    __syncthreads();

    const int nl2 = tid & 63, og = tid >> 6;
    const size_t node2 = (size_t)b * NN + n0 + nl2;
    float tac[8];
    #pragma unroll
    for (int j = 0; j < 8; ++j) tac[j] = hop_b[og * 8 + j];
    #pragma unroll
    for (int kc = 0; kc < 8; ++kc) {
        float4 hv4 = *(const float4*)&hsh[nl2][kc * 4];
        const float* hv = (const float*)&hv4;
        #pragma unroll
        for (int p = 0; p < 4; ++p) {
            #pragma unroll
            for (int j = 0; j < 8; ++j) tac[j] += hv[p] * hw[(kc * 4 + p) * 32 + og * 8 + j];
        }
    }
    float* out2 = out + (size_t)BB * NN * 32;
    *(float4*)&out[node2 * 32 + og * 8]     = *(const float4*)&hsh[nl2][og * 8];
    *(float4*)&out[node2 * 32 + og * 8 + 4] = *(const float4*)&hsh[nl2][og * 8 + 4];
    float4 t0; float* t0p = (float*)&t0;
    t0p[0]=tac[0]; t0p[1]=tac[1]; t0p[2]=tac[2]; t0p[3]=tac[3];
    *(float4*)&out2[node2 * 32 + og * 8] = t0;
    t0p[0]=tac[4]; t0p[1]=tac[5]; t0p[2]=tac[6]; t0p[3]=tac[7];
    *(float4*)&out2[node2 * 32 + og * 8 + 4] = t0;
}

// ---------------------------------------------------------------------------
extern "C" void kernel_launch(void* const* d_in, const int* in_sizes, int n_in,
                              void* d_out, int out_size, void* d_ws, size_t ws_size,
                              hipStream_t stream)
{
    const float* xt     = (const float*)d_in[0];
    const float* s1     = (const float*)d_in[1];
    const float* s2     = (const float*)d_in[2];
    const float* ge     = (const float*)d_in[3];
    const float* sup    = (const float*)d_in[4];
    const float* mlp_w  = (const float*)d_in[5];
    const float* mlp_b  = (const float*)d_in[6];
    const float* gate_w = (const float*)d_in[7];
    const float* gate_b = (const float*)d_in[8];
    const float* upd_w  = (const float*)d_in[9];
    const float* upd_b  = (const float*)d_in[10];
    const float* hop_w  = (const float*)d_in[11];
    const float* hop_b  = (const float*)d_in[12];
    float* out = (float*)d_out;

    char* ws = (char*)d_ws;
    size_t off = 0;
    auto alloc = [&](size_t bytes) -> void* {
        void* p = ws + off;
        off += (bytes + 255) & ~(size_t)255;
        return p;
    };
    bf16*  T     = (bf16*) alloc((size_t)BB * KT * NN * 2);
    float* state = (float*)alloc((size_t)BB * NN * 32 * 4);
    float* rT    = (float*)alloc((size_t)BB * 32 * NN * 4);
    bf16*  Wg    = (bf16*) alloc((size_t)96 * KT * 2);
    bf16*  Wu    = (bf16*) alloc((size_t)32 * KT * 2);
    bf16*  Abf   = (bf16*) (ws + off);
    const bool useA = (off + (size_t)16 * NN * NN * 2) <= ws_size;

    prep_weights<<<156, 256, 0, stream>>>(gate_w, upd_w, Wg, Wu);
    prep_nodes<<<256, 256, 0, stream>>>(xt, s1, s2, ge, mlp_w, mlp_b, state, T);

    if (useA) {
        gemm_cheb<1><<<dim3(32, 16), 256, 0, stream>>>(sup, Abf, T, 0, 0, 1, 3);
        gemm_cheb<2><<<dim3(32, 16), 256, 0, stream>>>(sup, Abf, T, 1, 3, 2, 4);
        proj_gate<<<dim3(32, 8), 256, 0, stream>>>(T, Wg, gate_b, s1, s2, T, rT);
        gemm_cheb<2><<<dim3(32, 16), 256, 0, stream>>>(sup, Abf, T, 0, 0, 1, 3);
        gemm_cheb<2><<<dim3(32, 16), 256, 0, stream>>>(sup, Abf, T, 1, 3, 2, 4);
    } else {
        gemm_cheb<0><<<dim3(32, 16), 256, 0, stream>>>(sup, Abf, T, 0, 0, 1, 3);
        gemm_cheb<0><<<dim3(32, 16), 256, 0, stream>>>(sup, Abf, T, 1, 3, 2, 4);
        proj_gate<<<dim3(32, 8), 256, 0, stream>>>(T, Wg, gate_b, s1, s2, T, rT);
        gemm_cheb<0><<<dim3(32, 16), 256, 0, stream>>>(sup, Abf, T, 0, 0, 1, 3);
        gemm_cheb<0><<<dim3(32, 16), 256, 0, stream>>>(sup, Abf, T, 1, 3, 2, 4);
    }
    proj_upd<<<dim3(32, 8), 256, 0, stream>>>(T, Wu, upd_b, state, rT, hop_w, hop_b, out);
}